// Round 1
// baseline (1489.723 us; speedup 1.0000x reference)
//
#include <hip/hip_runtime.h>
#include <hip/hip_bf16.h>
#include <math.h>

#define DEV __device__ __forceinline__

DEV float sigf(float x)   { return 1.0f / (1.0f + __expf(-x)); }
DEV float tanhft(float x) { return 1.0f - 2.0f / (__expf(2.0f * x) + 1.0f); }

// ---------------------------------------------------------------------------
// prep: transpose + k-pack LSTM weights for coalesced streaming.
// packed layout: wp[kc*2048 + col*4 + kk]  == w[col*128 + kc*4 + kk]
// wt_ih0[f*512 + col] == w_ih0[col*5 + f];  bias = b_ih + b_hh
// ---------------------------------------------------------------------------
__global__ __launch_bounds__(256) void prep_kernel(
    const float* __restrict__ w_hh0, const float* __restrict__ w_ih1,
    const float* __restrict__ w_hh1, const float* __restrict__ w_ih0,
    const float* __restrict__ b_ih0, const float* __restrict__ b_hh0,
    const float* __restrict__ b_ih1, const float* __restrict__ b_hh1,
    float* __restrict__ wp0, float* __restrict__ wp1i, float* __restrict__ wp1h,
    float* __restrict__ wt_ih0, float* __restrict__ bias0, float* __restrict__ bias1)
{
    int i = blockIdx.x * 256 + threadIdx.x;
    if (i < 65536) {
        int col = (i >> 2) & 511;
        int k   = ((i >> 11) << 2) | (i & 3);
        wp0[i]  = w_hh0[col * 128 + k];
        wp1i[i] = w_ih1[col * 128 + k];
        wp1h[i] = w_hh1[col * 128 + k];
    } else if (i < 65536 + 2560) {
        int j = i - 65536;
        int f = j >> 9, col = j & 511;
        wt_ih0[j] = w_ih0[col * 5 + f];
    } else if (i < 65536 + 2560 + 512) {
        int c = i - 65536 - 2560;
        bias0[c] = b_ih0[c] + b_hh0[c];
        bias1[c] = b_ih1[c] + b_hh1[c];
    }
}

// ---------------------------------------------------------------------------
// LSTM: both layers, all 60 steps, 4 batch rows / block, 256 blocks.
// Thread owns gate cols (tid, tid+256). h broadcast from LDS; weights
// streamed coalesced from L2 with one-chunk register prefetch.
// NOTE: prefetch reads up to 8KB past each wp buffer -> always into the
// next ws buffer (wp0->wp1i->wp1h->wt_ih0), never out of ws. Never used.
// ---------------------------------------------------------------------------
DEV void gate_gemm128(float accA[4], float accB[4], const float* __restrict__ wp,
                      const float (*hs)[128], int cA, int cB)
{
    float4 wA = *(const float4*)(wp + cA * 4);
    float4 wB = *(const float4*)(wp + cB * 4);
#pragma unroll 4
    for (int kc = 0; kc < 32; ++kc) {
        float4 nA = *(const float4*)(wp + (kc + 1) * 2048 + cA * 4);
        float4 nB = *(const float4*)(wp + (kc + 1) * 2048 + cB * 4);
#pragma unroll
        for (int r = 0; r < 4; ++r) {
            float4 h = *(const float4*)(&hs[r][kc * 4]);
            accA[r] = fmaf(h.x, wA.x, accA[r]);
            accA[r] = fmaf(h.y, wA.y, accA[r]);
            accA[r] = fmaf(h.z, wA.z, accA[r]);
            accA[r] = fmaf(h.w, wA.w, accA[r]);
            accB[r] = fmaf(h.x, wB.x, accB[r]);
            accB[r] = fmaf(h.y, wB.y, accB[r]);
            accB[r] = fmaf(h.z, wB.z, accB[r]);
            accB[r] = fmaf(h.w, wB.w, accB[r]);
        }
        wA = nA; wB = nB;
    }
}

DEV void lstm_update(int tid, const float (*gbuf)[512], float (*cs)[128], float (*hs)[128])
{
#pragma unroll
    for (int s = 0; s < 2; ++s) {
        int u = tid + s * 256;
        int r = u >> 7, j = u & 127;
        float gi = gbuf[r][j];
        float gf = gbuf[r][128 + j];
        float gg = gbuf[r][256 + j];
        float go = gbuf[r][384 + j];
        float cn = sigf(gf) * cs[r][j] + sigf(gi) * tanhft(gg);
        cs[r][j] = cn;
        hs[r][j] = sigf(go) * tanhft(cn);
    }
}

__global__ __launch_bounds__(256) void lstm_kernel(
    const float* __restrict__ x,
    const float* __restrict__ wp0, const float* __restrict__ wt_ih0,
    const float* __restrict__ bias0,
    const float* __restrict__ wp1i, const float* __restrict__ wp1h,
    const float* __restrict__ bias1,
    float* __restrict__ h2out)
{
    __shared__ __align__(16) float h0s[4][128], c0s[4][128], h1s[4][128], c1s[4][128];
    __shared__ __align__(16) float gbuf[4][512];
    __shared__ float xt[4][8];
    const int tid = threadIdx.x;
    const int b0 = blockIdx.x * 4;
    const int cA = tid, cB = tid + 256;

    for (int i = tid; i < 512; i += 256) {
        int r = i >> 7, j = i & 127;
        h0s[r][j] = 0.f; c0s[r][j] = 0.f; h1s[r][j] = 0.f; c1s[r][j] = 0.f;
    }
    __syncthreads();

    const float bA0 = bias0[cA], bB0 = bias0[cB];
    const float bA1 = bias1[cA], bB1 = bias1[cB];

    for (int t = 0; t < 60; ++t) {
        if (tid < 20) {
            int r = tid / 5, f = tid % 5;
            xt[r][f] = x[(b0 + r) * 300 + t * 5 + f];
        }
        __syncthreads();

        // ---- layer 0 gates: g = x_t @ w_ih0^T + h0 @ w_hh0^T + bias0
        float accA[4] = {bA0, bA0, bA0, bA0};
        float accB[4] = {bB0, bB0, bB0, bB0};
#pragma unroll
        for (int f = 0; f < 5; ++f) {
            float w0 = wt_ih0[f * 512 + cA];
            float w1 = wt_ih0[f * 512 + cB];
#pragma unroll
            for (int r = 0; r < 4; ++r) {
                accA[r] = fmaf(xt[r][f], w0, accA[r]);
                accB[r] = fmaf(xt[r][f], w1, accB[r]);
            }
        }
        gate_gemm128(accA, accB, wp0, (const float(*)[128])h0s, cA, cB);
#pragma unroll
        for (int r = 0; r < 4; ++r) { gbuf[r][cA] = accA[r]; gbuf[r][cB] = accB[r]; }
        __syncthreads();
        lstm_update(tid, (const float(*)[512])gbuf, c0s, h0s);
        __syncthreads();   // h0s now holds seq_t

        // ---- layer 1 gates: g = seq_t @ w_ih1^T + h1 @ w_hh1^T + bias1
        float aA[4] = {bA1, bA1, bA1, bA1};
        float aB[4] = {bB1, bB1, bB1, bB1};
        gate_gemm128(aA, aB, wp1i, (const float(*)[128])h0s, cA, cB);
        gate_gemm128(aA, aB, wp1h, (const float(*)[128])h1s, cA, cB);
#pragma unroll
        for (int r = 0; r < 4; ++r) { gbuf[r][cA] = aA[r]; gbuf[r][cB] = aB[r]; }
        __syncthreads();
        lstm_update(tid, (const float(*)[512])gbuf, c1s, h1s);
        __syncthreads();
    }

    for (int i = tid; i < 512; i += 256) {
        int r = i >> 7, j = i & 127;
        h2out[(b0 + r) * 128 + j] = h1s[r][j];
    }
}

// ---------------------------------------------------------------------------
// base = tanh(relu(h2 @ pw1^T + pb1) @ pw2^T + pb2)   (1024 x 32)
// ---------------------------------------------------------------------------
__global__ __launch_bounds__(64) void phase2_kernel(
    const float* __restrict__ h2, const float* __restrict__ pw1,
    const float* __restrict__ pb1, const float* __restrict__ pw2,
    const float* __restrict__ pb2, float* __restrict__ base)
{
    __shared__ float hs[128], p1[64];
    int b = blockIdx.x, tid = threadIdx.x;
    hs[tid] = h2[b * 128 + tid];
    hs[tid + 64] = h2[b * 128 + 64 + tid];
    __syncthreads();
    float acc = pb1[tid];
#pragma unroll 4
    for (int k = 0; k < 128; ++k) acc = fmaf(hs[k], pw1[tid * 128 + k], acc);
    p1[tid] = fmaxf(acc, 0.f);
    __syncthreads();
    if (tid < 32) {
        float a2 = pb2[tid];
#pragma unroll 4
        for (int k = 0; k < 64; ++k) a2 = fmaf(p1[k], pw2[tid * 64 + k], a2);
        base[b * 32 + tid] = tanhft(a2);
    }
}

// ---------------------------------------------------------------------------
// W_eff^T[j][n] = sum_{k: conn_idx[n,k]%32==j} conn_w[n,k]
// (all_act[:, idx] == base[:, idx % 32] because base is tiled with period 32)
// ---------------------------------------------------------------------------
__global__ __launch_bounds__(128) void weff_kernel(
    const int* __restrict__ conn_idx, const float* __restrict__ conn_w,
    float* __restrict__ weffT)
{
    __shared__ float s[128 * 33];
    int tid = threadIdx.x;
    int n = blockIdx.x * 128 + tid;
    float* sr = &s[tid * 33];
#pragma unroll
    for (int j = 0; j < 32; ++j) sr[j] = 0.f;
    if (n < 2500) {
        for (int k = 0; k < 50; ++k) {
            int idx = conn_idx[n * 50 + k];
            sr[idx & 31] += conn_w[n * 50 + k];
        }
        for (int j = 0; j < 32; ++j) weffT[j * 2500 + n] = sr[j];
    }
}

// ---------------------------------------------------------------------------
// z = (base @ W_eff^T) * sens; a = per-group activation. a stored [b][n].
// grid: 64 b-tiles(16 rows) x 10 n-tiles(256)
// ---------------------------------------------------------------------------
__global__ __launch_bounds__(256) void za_kernel(
    const float* __restrict__ base, const float* __restrict__ weffT,
    const float* __restrict__ sens, const float* __restrict__ thr,
    float* __restrict__ amat)
{
    __shared__ float bs[16][32];
    int tid = threadIdx.x;
    int bb = blockIdx.x / 10, nb = blockIdx.x % 10;
    int n = nb * 256 + tid;
    bool nv = n < 2500;
    int nn = nv ? n : 0;
    for (int i = tid; i < 512; i += 256) bs[i >> 5][i & 31] = base[bb * 512 + i];
    __syncthreads();
    float w[32];
#pragma unroll
    for (int j = 0; j < 32; ++j) w[j] = weffT[j * 2500 + nn];
    float sn = sens[nn], tn = thr[nn];
    int g = (n < 800) ? 0 : (n < 1500) ? 1 : (n < 2100) ? 2 : 3;
#pragma unroll 2
    for (int r = 0; r < 16; ++r) {
        float z = 0.f;
#pragma unroll
        for (int j = 0; j < 32; ++j) z = fmaf(bs[r][j], w[j], z);
        z *= sn;
        float av;
        if (g == 0)      av = sigf(z - tn);
        else if (g == 1) av = tanhft(z);
        else if (g == 2) av = fmaxf(z - tn, 0.f);
        else             av = sigf(z);
        if (nv) amat[(bb * 16 + r) * 2500 + n] = av;
    }
}

// ---------------------------------------------------------------------------
// t1 = relu(a @ iw1^T + ib1): M=1024 N=256 K=2500. 32x32 tile, 2x2/thread.
// ---------------------------------------------------------------------------
__global__ __launch_bounds__(256) void gemm_iw1_kernel(
    const float* __restrict__ amat, const float* __restrict__ iw1,
    const float* __restrict__ ib1, float* __restrict__ t1)
{
    __shared__ float sa[32][65], sw[32][65];
    int tid = threadIdx.x;
    int tx = tid & 15, ty = tid >> 4;
    int col0 = blockIdx.x * 32, row0 = blockIdx.y * 32;
    int kk = tid & 63, rr = tid >> 6;
    float acc00 = 0, acc01 = 0, acc10 = 0, acc11 = 0;
    for (int k0 = 0; k0 < 2500; k0 += 64) {
        int k = k0 + kk;
        bool kv = k < 2500;
#pragma unroll
        for (int p = 0; p < 8; ++p) {
            int r = rr + p * 4;
            sa[r][kk] = kv ? amat[(row0 + r) * 2500 + k] : 0.f;
            sw[r][kk] = kv ? iw1[(col0 + r) * 2500 + k] : 0.f;
        }
        __syncthreads();
#pragma unroll 8
        for (int k2 = 0; k2 < 64; ++k2) {
            float a0 = sa[ty * 2][k2],     a1 = sa[ty * 2 + 1][k2];
            float w0 = sw[tx * 2][k2],     w1 = sw[tx * 2 + 1][k2];
            acc00 = fmaf(a0, w0, acc00);
            acc01 = fmaf(a0, w1, acc01);
            acc10 = fmaf(a1, w0, acc10);
            acc11 = fmaf(a1, w1, acc11);
        }
        __syncthreads();
    }
    int row = row0 + ty * 2, col = col0 + tx * 2;
    float b0v = ib1[col], b1v = ib1[col + 1];
    t1[row * 256 + col]           = fmaxf(acc00 + b0v, 0.f);
    t1[row * 256 + col + 1]       = fmaxf(acc01 + b1v, 0.f);
    t1[(row + 1) * 256 + col]     = fmaxf(acc10 + b0v, 0.f);
    t1[(row + 1) * 256 + col + 1] = fmaxf(acc11 + b1v, 0.f);
}

// ---------------------------------------------------------------------------
// t2 = relu(t1@iw2^T+ib2); integ = tanh(t2@iw3^T+ib3); 5 heads + overall
// out layout per row: [trend 0:3 | pat 3:9 | key 9:13 | vol 13 | conf 14 |
//                      overall 15 | means 16:20]
// ---------------------------------------------------------------------------
__global__ __launch_bounds__(64) void final_kernel(
    const float* __restrict__ t1, const float* __restrict__ iw2,
    const float* __restrict__ ib2, const float* __restrict__ iw3,
    const float* __restrict__ ib3,
    const float* __restrict__ hw_trend, const float* __restrict__ hb_trend,
    const float* __restrict__ hw_pat,   const float* __restrict__ hb_pat,
    const float* __restrict__ hw_key,   const float* __restrict__ hb_key,
    const float* __restrict__ hw_vol,   const float* __restrict__ hb_vol,
    const float* __restrict__ hw_conf,  const float* __restrict__ hb_conf,
    float* __restrict__ out)
{
    __shared__ float t1s[256], t2s[64], igs[32];
    int b = blockIdx.x, tid = threadIdx.x;
#pragma unroll
    for (int i = 0; i < 4; ++i) t1s[tid + i * 64] = t1[b * 256 + tid + i * 64];
    __syncthreads();
    float acc = ib2[tid];
#pragma unroll 4
    for (int k = 0; k < 256; ++k) acc = fmaf(t1s[k], iw2[tid * 256 + k], acc);
    t2s[tid] = fmaxf(acc, 0.f);
    __syncthreads();
    if (tid < 32) {
        float a2 = ib3[tid];
#pragma unroll 4
        for (int k = 0; k < 64; ++k) a2 = fmaf(t2s[k], iw3[tid * 64 + k], a2);
        igs[tid] = tanhft(a2);
    }
    __syncthreads();
    if (tid < 15) {
        const float* w; const float* bb; int j, off;
        if (tid < 3)        { w = hw_trend; bb = hb_trend; j = tid;     off = 0; }
        else if (tid < 9)   { w = hw_pat;   bb = hb_pat;   j = tid - 3; off = 3; }
        else if (tid < 13)  { w = hw_key;   bb = hb_key;   j = tid - 9; off = 9; }
        else if (tid == 13) { w = hw_vol;   bb = hb_vol;   j = 0;       off = 13; }
        else                { w = hw_conf;  bb = hb_conf;  j = 0;       off = 14; }
        float a3 = bb[j];
#pragma unroll
        for (int k = 0; k < 32; ++k) a3 = fmaf(igs[k], w[j * 32 + k], a3);
        out[b * 20 + off + j] = a3;
        if (tid == 14) out[b * 20 + 15] = sigf(a3);
    }
}

// ---------------------------------------------------------------------------
// group means of a -> out[:, 16:20]
// ---------------------------------------------------------------------------
__global__ __launch_bounds__(256) void means_kernel(
    const float* __restrict__ amat, float* __restrict__ out)
{
    __shared__ float red[256];
    int b = blockIdx.x, tid = threadIdx.x;
    float parts[4] = {0.f, 0.f, 0.f, 0.f};
    for (int n = tid; n < 2500; n += 256) {
        float v = amat[b * 2500 + n];
        if (n < 800)       parts[0] += v;
        else if (n < 1500) parts[1] += v;
        else if (n < 2100) parts[2] += v;
        else               parts[3] += v;
    }
    const float inv[4] = {1.f / 800.f, 1.f / 700.f, 1.f / 600.f, 1.f / 400.f};
#pragma unroll
    for (int g = 0; g < 4; ++g) {
        red[tid] = parts[g];
        __syncthreads();
        for (int s = 128; s > 0; s >>= 1) {
            if (tid < s) red[tid] += red[tid + s];
            __syncthreads();
        }
        if (tid == 0) out[b * 20 + 16 + g] = red[0] * inv[g];
        __syncthreads();
    }
}

// ---------------------------------------------------------------------------
extern "C" void kernel_launch(void* const* d_in, const int* in_sizes, int n_in,
                              void* d_out, int out_size, void* d_ws, size_t ws_size,
                              hipStream_t stream)
{
    const float* x        = (const float*)d_in[0];
    const int*   conn_idx = (const int*)  d_in[1];
    const float* w_ih0    = (const float*)d_in[2];
    const float* w_hh0    = (const float*)d_in[3];
    const float* b_ih0    = (const float*)d_in[4];
    const float* b_hh0    = (const float*)d_in[5];
    const float* w_ih1    = (const float*)d_in[6];
    const float* w_hh1    = (const float*)d_in[7];
    const float* b_ih1    = (const float*)d_in[8];
    const float* b_hh1    = (const float*)d_in[9];
    const float* pw1      = (const float*)d_in[10];
    const float* pb1      = (const float*)d_in[11];
    const float* pw2      = (const float*)d_in[12];
    const float* pb2      = (const float*)d_in[13];
    const float* conn_w   = (const float*)d_in[14];
    const float* sens     = (const float*)d_in[15];
    const float* thr      = (const float*)d_in[16];
    const float* iw1      = (const float*)d_in[17];
    const float* ib1      = (const float*)d_in[18];
    const float* iw2      = (const float*)d_in[19];
    const float* ib2      = (const float*)d_in[20];
    const float* iw3      = (const float*)d_in[21];
    const float* ib3      = (const float*)d_in[22];
    const float* hw_trend = (const float*)d_in[23];
    const float* hb_trend = (const float*)d_in[24];
    const float* hw_pat   = (const float*)d_in[25];
    const float* hb_pat   = (const float*)d_in[26];
    const float* hw_key   = (const float*)d_in[27];
    const float* hb_key   = (const float*)d_in[28];
    const float* hw_vol   = (const float*)d_in[29];
    const float* hb_vol   = (const float*)d_in[30];
    const float* hw_conf  = (const float*)d_in[31];
    const float* hb_conf  = (const float*)d_in[32];
    float* out = (float*)d_out;
    float* ws  = (float*)d_ws;

    // ws layout (floats); total 3,266,176 floats = ~12.5 MB
    float* wp0    = ws;             // 65536
    float* wp1i   = ws + 65536;     // 65536
    float* wp1h   = ws + 131072;    // 65536
    float* wt_ih0 = ws + 196608;    // 2560 (also prefetch overflow landing zone)
    float* bias0  = ws + 199168;    // 512
    float* bias1  = ws + 199680;    // 512
    float* h2     = ws + 200192;    // 131072
    float* base_  = ws + 331264;    // 32768
    float* weffT  = ws + 364032;    // 80000
    float* t1     = ws + 444032;    // 262144
    float* amat   = ws + 706176;    // 2560000

    prep_kernel<<<268, 256, 0, stream>>>(w_hh0, w_ih1, w_hh1, w_ih0,
                                         b_ih0, b_hh0, b_ih1, b_hh1,
                                         wp0, wp1i, wp1h, wt_ih0, bias0, bias1);
    lstm_kernel<<<256, 256, 0, stream>>>(x, wp0, wt_ih0, bias0, wp1i, wp1h, bias1, h2);
    phase2_kernel<<<1024, 64, 0, stream>>>(h2, pw1, pb1, pw2, pb2, base_);
    weff_kernel<<<20, 128, 0, stream>>>(conn_idx, conn_w, weffT);
    za_kernel<<<640, 256, 0, stream>>>(base_, weffT, sens, thr, amat);
    gemm_iw1_kernel<<<dim3(8, 32), 256, 0, stream>>>(amat, iw1, ib1, t1);
    final_kernel<<<1024, 64, 0, stream>>>(t1, iw2, ib2, iw3, ib3,
                                          hw_trend, hb_trend, hw_pat, hb_pat,
                                          hw_key, hb_key, hw_vol, hb_vol,
                                          hw_conf, hb_conf, out);
    means_kernel<<<1024, 256, 0, stream>>>(amat, out);
}

// Round 2
// 761.052 us; speedup vs baseline: 1.9575x; 1.9575x over previous
//
#include <hip/hip_runtime.h>
#include <hip/hip_bf16.h>
#include <math.h>

#define DEV __device__ __forceinline__

typedef _Float16 h2_t __attribute__((ext_vector_type(2)));
union F4H { float4 f4; h2_t h2[4]; };
union HP  { _Float16 h[2]; unsigned int u; };

DEV float sigf(float x)   { return 1.0f / (1.0f + __expf(-x)); }
DEV float tanhft(float x) { return 1.0f - 2.0f / (__expf(2.0f * x) + 1.0f); }
DEV float fdot2(h2_t a, h2_t b, float c) { return __builtin_amdgcn_fdot2(a, b, c, false); }

// LDS-only barrier: drain LDS ops but leave global loads (vmcnt) in flight.
// All cross-thread communication in lstm_kernel goes through LDS, so this is
// sufficient and lets weight prefetches stay outstanding across the barrier.
DEV void bar_lds() {
    asm volatile("s_waitcnt lgkmcnt(0)" ::: "memory");
    __builtin_amdgcn_s_barrier();
}

// ---------------------------------------------------------------------------
// prep: convert LSTM recurrent weights to f16, k-pack for coalesced float4
// streaming. Layout (as uint half2-pairs):
//   wph[(kpc*512 + col)*4 + p] = half2(W[col][kpc*8+2p], W[col][kpc*8+2p+1])
// so float4 chunk (kpc, col) holds k = kpc*8 .. kpc*8+7 of column col.
// wt_ih0[f*512 + col] = w_ih0[col][f] (fp32);  bias = b_ih + b_hh.
// ---------------------------------------------------------------------------
__global__ __launch_bounds__(256) void prep_kernel(
    const float* __restrict__ w_hh0, const float* __restrict__ w_ih1,
    const float* __restrict__ w_hh1, const float* __restrict__ w_ih0,
    const float* __restrict__ b_ih0, const float* __restrict__ b_hh0,
    const float* __restrict__ b_ih1, const float* __restrict__ b_hh1,
    unsigned int* __restrict__ wph0, unsigned int* __restrict__ wph1i,
    unsigned int* __restrict__ wph1h,
    float* __restrict__ wt_ih0, float* __restrict__ bias0, float* __restrict__ bias1)
{
    int i = blockIdx.x * 256 + threadIdx.x;
    if (i < 32768) {
        int p   = i & 3;
        int col = (i >> 2) & 511;
        int kpc = i >> 11;
        int k   = kpc * 8 + p * 2;
        HP a, b, c;
        a.h[0] = (_Float16)w_hh0[col * 128 + k];
        a.h[1] = (_Float16)w_hh0[col * 128 + k + 1];
        b.h[0] = (_Float16)w_ih1[col * 128 + k];
        b.h[1] = (_Float16)w_ih1[col * 128 + k + 1];
        c.h[0] = (_Float16)w_hh1[col * 128 + k];
        c.h[1] = (_Float16)w_hh1[col * 128 + k + 1];
        wph0[i]  = a.u;
        wph1i[i] = b.u;
        wph1h[i] = c.u;
    } else if (i < 32768 + 2560) {
        int j = i - 32768;
        int f = j >> 9, col = j & 511;
        wt_ih0[j] = w_ih0[col * 5 + f];
    } else if (i < 32768 + 2560 + 512) {
        int c = i - 32768 - 2560;
        bias0[c] = b_ih0[c] + b_hh0[c];
        bias1[c] = b_ih1[c] + b_hh1[c];
    }
}

// ---------------------------------------------------------------------------
// LSTM: both layers, 60 steps, 4 batch rows/block, 256 blocks x 512 threads.
// Thread owns one gate column (tid). h stored f16 in LDS (broadcast reads),
// c stays fp32 in registers of the updating thread. Weights streamed from L2
// as f16 float4 chunks, prefetched across lgkm-only barriers.
// ---------------------------------------------------------------------------
DEV void dot_mat(float acc[4], const float4 w[16], const _Float16 (*hs)[128])
{
#pragma unroll
    for (int i = 0; i < 16; ++i) {
        F4H wc; wc.f4 = w[i];
#pragma unroll
        for (int r = 0; r < 4; ++r) {
            F4H hc; hc.f4 = *(const float4*)(&hs[r][i * 8]);
            acc[r] = fdot2(wc.h2[0], hc.h2[0], acc[r]);
            acc[r] = fdot2(wc.h2[1], hc.h2[1], acc[r]);
            acc[r] = fdot2(wc.h2[2], hc.h2[2], acc[r]);
            acc[r] = fdot2(wc.h2[3], hc.h2[3], acc[r]);
        }
    }
}

__global__ __launch_bounds__(512, 2) void lstm_kernel(
    const float* __restrict__ x,
    const unsigned int* __restrict__ wph0, const float* __restrict__ wt_ih0,
    const float* __restrict__ bias0,
    const unsigned int* __restrict__ wph1i, const unsigned int* __restrict__ wph1h,
    const float* __restrict__ bias1,
    float* __restrict__ h2out)
{
    __shared__ __align__(16) float xs[1200];
    __shared__ __align__(16) _Float16 h0h[4][128];
    __shared__ __align__(16) _Float16 h1h[4][128];
    __shared__ __align__(16) float gbuf[4][512];
    const int tid = threadIdx.x;
    const int b0  = blockIdx.x * 4;
    const int c   = tid;
    const int r_u = tid >> 7, j_u = tid & 127;

    for (int i = tid; i < 1200; i += 512) xs[i] = x[b0 * 300 + i];
    if (tid < 256) { ((float*)h0h)[tid] = 0.f; ((float*)h1h)[tid] = 0.f; }

    const float4* w04  = (const float4*)wph0;
    const float4* w1i4 = (const float4*)wph1i;
    const float4* w1h4 = (const float4*)wph1h;

    float wt[5];
#pragma unroll
    for (int f = 0; f < 5; ++f) wt[f] = wt_ih0[f * 512 + c];
    const float b0v = bias0[c], b1v = bias1[c];
    float c0 = 0.f, c1 = 0.f, h1f = 0.f;

    // preload step-0 layer-0 weights
    float4 w0[16];
#pragma unroll
    for (int i = 0; i < 16; ++i) w0[i] = w04[i * 512 + c];

    bar_lds();

    for (int t = 0; t < 60; ++t) {
        // ---- layer 0 gates: bias + x-part + h0 @ w_hh0^T
        float acc0[4] = {b0v, b0v, b0v, b0v};
#pragma unroll
        for (int f = 0; f < 5; ++f) {
#pragma unroll
            for (int r = 0; r < 4; ++r)
                acc0[r] = fmaf(xs[r * 300 + t * 5 + f], wt[f], acc0[r]);
        }
        // prefetch layer-1 input weights (in flight across the update barrier)
        float4 w1i[16];
#pragma unroll
        for (int i = 0; i < 16; ++i) w1i[i] = w1i4[i * 512 + c];

        dot_mat(acc0, w0, (const _Float16(*)[128])h0h);
#pragma unroll
        for (int r = 0; r < 4; ++r) gbuf[r][c] = acc0[r];
        bar_lds();

        // ---- layer 0 update (thread owns element (r_u, j_u); c0 in reg)
        {
            float gi = gbuf[r_u][j_u];
            float gf = gbuf[r_u][128 + j_u];
            float gg = gbuf[r_u][256 + j_u];
            float go = gbuf[r_u][384 + j_u];
            c0 = sigf(gf) * c0 + sigf(gi) * tanhft(gg);
            float h = sigf(go) * tanhft(c0);
            h0h[r_u][j_u] = (_Float16)h;
        }
        bar_lds();

        // ---- layer 1 gates: bias + h0new @ w_ih1^T + h1 @ w_hh1^T
        float acc1[4] = {b1v, b1v, b1v, b1v};
        float4 w1h[16];
#pragma unroll
        for (int i = 0; i < 16; ++i) w1h[i] = w1h4[i * 512 + c];

        dot_mat(acc1, w1i, (const _Float16(*)[128])h0h);

        // prefetch next step's layer-0 weights (in flight across update-1)
#pragma unroll
        for (int i = 0; i < 16; ++i) w0[i] = w04[i * 512 + c];

        dot_mat(acc1, w1h, (const _Float16(*)[128])h1h);
#pragma unroll
        for (int r = 0; r < 4; ++r) gbuf[r][c] = acc1[r];
        bar_lds();

        // ---- layer 1 update
        {
            float gi = gbuf[r_u][j_u];
            float gf = gbuf[r_u][128 + j_u];
            float gg = gbuf[r_u][256 + j_u];
            float go = gbuf[r_u][384 + j_u];
            c1 = sigf(gf) * c1 + sigf(gi) * tanhft(gg);
            float h = sigf(go) * tanhft(c1);
            h1h[r_u][j_u] = (_Float16)h;
            h1f = h;
        }
        bar_lds();
    }

    h2out[(b0 + r_u) * 128 + j_u] = h1f;
}

// ---------------------------------------------------------------------------
// base = tanh(relu(h2 @ pw1^T + pb1) @ pw2^T + pb2)   (1024 x 32)
// ---------------------------------------------------------------------------
__global__ __launch_bounds__(64) void phase2_kernel(
    const float* __restrict__ h2, const float* __restrict__ pw1,
    const float* __restrict__ pb1, const float* __restrict__ pw2,
    const float* __restrict__ pb2, float* __restrict__ base)
{
    __shared__ float hs[128], p1[64];
    int b = blockIdx.x, tid = threadIdx.x;
    hs[tid] = h2[b * 128 + tid];
    hs[tid + 64] = h2[b * 128 + 64 + tid];
    __syncthreads();
    float acc = pb1[tid];
#pragma unroll 4
    for (int k = 0; k < 128; ++k) acc = fmaf(hs[k], pw1[tid * 128 + k], acc);
    p1[tid] = fmaxf(acc, 0.f);
    __syncthreads();
    if (tid < 32) {
        float a2 = pb2[tid];
#pragma unroll 4
        for (int k = 0; k < 64; ++k) a2 = fmaf(p1[k], pw2[tid * 64 + k], a2);
        base[b * 32 + tid] = tanhft(a2);
    }
}

// ---------------------------------------------------------------------------
// W_eff^T[j][n] = sum_{k: conn_idx[n,k]%32==j} conn_w[n,k]
// ---------------------------------------------------------------------------
__global__ __launch_bounds__(128) void weff_kernel(
    const int* __restrict__ conn_idx, const float* __restrict__ conn_w,
    float* __restrict__ weffT)
{
    __shared__ float s[128 * 33];
    int tid = threadIdx.x;
    int n = blockIdx.x * 128 + tid;
    float* sr = &s[tid * 33];
#pragma unroll
    for (int j = 0; j < 32; ++j) sr[j] = 0.f;
    if (n < 2500) {
        for (int k = 0; k < 50; ++k) {
            int idx = conn_idx[n * 50 + k];
            sr[idx & 31] += conn_w[n * 50 + k];
        }
        for (int j = 0; j < 32; ++j) weffT[j * 2500 + n] = sr[j];
    }
}

// ---------------------------------------------------------------------------
// z = (base @ W_eff^T) * sens; a = per-group activation. a stored [b][n].
// ---------------------------------------------------------------------------
__global__ __launch_bounds__(256) void za_kernel(
    const float* __restrict__ base, const float* __restrict__ weffT,
    const float* __restrict__ sens, const float* __restrict__ thr,
    float* __restrict__ amat)
{
    __shared__ float bs[16][32];
    int tid = threadIdx.x;
    int bb = blockIdx.x / 10, nb = blockIdx.x % 10;
    int n = nb * 256 + tid;
    bool nv = n < 2500;
    int nn = nv ? n : 0;
    for (int i = tid; i < 512; i += 256) bs[i >> 5][i & 31] = base[bb * 512 + i];
    __syncthreads();
    float w[32];
#pragma unroll
    for (int j = 0; j < 32; ++j) w[j] = weffT[j * 2500 + nn];
    float sn = sens[nn], tn = thr[nn];
    int g = (n < 800) ? 0 : (n < 1500) ? 1 : (n < 2100) ? 2 : 3;
#pragma unroll 2
    for (int r = 0; r < 16; ++r) {
        float z = 0.f;
#pragma unroll
        for (int j = 0; j < 32; ++j) z = fmaf(bs[r][j], w[j], z);
        z *= sn;
        float av;
        if (g == 0)      av = sigf(z - tn);
        else if (g == 1) av = tanhft(z);
        else if (g == 2) av = fmaxf(z - tn, 0.f);
        else             av = sigf(z);
        if (nv) amat[(bb * 16 + r) * 2500 + n] = av;
    }
}

// ---------------------------------------------------------------------------
// t1 = relu(a @ iw1^T + ib1): M=1024 N=256 K=2500.
// ---------------------------------------------------------------------------
__global__ __launch_bounds__(256) void gemm_iw1_kernel(
    const float* __restrict__ amat, const float* __restrict__ iw1,
    const float* __restrict__ ib1, float* __restrict__ t1)
{
    __shared__ float sa[32][65], sw[32][65];
    int tid = threadIdx.x;
    int tx = tid & 15, ty = tid >> 4;
    int col0 = blockIdx.x * 32, row0 = blockIdx.y * 32;
    int kk = tid & 63, rr = tid >> 6;
    float acc00 = 0, acc01 = 0, acc10 = 0, acc11 = 0;
    for (int k0 = 0; k0 < 2500; k0 += 64) {
        int k = k0 + kk;
        bool kv = k < 2500;
#pragma unroll
        for (int p = 0; p < 8; ++p) {
            int r = rr + p * 4;
            sa[r][kk] = kv ? amat[(row0 + r) * 2500 + k] : 0.f;
            sw[r][kk] = kv ? iw1[(col0 + r) * 2500 + k] : 0.f;
        }
        __syncthreads();
#pragma unroll 8
        for (int k2 = 0; k2 < 64; ++k2) {
            float a0 = sa[ty * 2][k2],     a1 = sa[ty * 2 + 1][k2];
            float w0 = sw[tx * 2][k2],     w1 = sw[tx * 2 + 1][k2];
            acc00 = fmaf(a0, w0, acc00);
            acc01 = fmaf(a0, w1, acc01);
            acc10 = fmaf(a1, w0, acc10);
            acc11 = fmaf(a1, w1, acc11);
        }
        __syncthreads();
    }
    int row = row0 + ty * 2, col = col0 + tx * 2;
    float b0v = ib1[col], b1v = ib1[col + 1];
    t1[row * 256 + col]           = fmaxf(acc00 + b0v, 0.f);
    t1[row * 256 + col + 1]       = fmaxf(acc01 + b1v, 0.f);
    t1[(row + 1) * 256 + col]     = fmaxf(acc10 + b0v, 0.f);
    t1[(row + 1) * 256 + col + 1] = fmaxf(acc11 + b1v, 0.f);
}

// ---------------------------------------------------------------------------
// t2 = relu(t1@iw2^T+ib2); integ = tanh(t2@iw3^T+ib3); 5 heads + overall
// ---------------------------------------------------------------------------
__global__ __launch_bounds__(64) void final_kernel(
    const float* __restrict__ t1, const float* __restrict__ iw2,
    const float* __restrict__ ib2, const float* __restrict__ iw3,
    const float* __restrict__ ib3,
    const float* __restrict__ hw_trend, const float* __restrict__ hb_trend,
    const float* __restrict__ hw_pat,   const float* __restrict__ hb_pat,
    const float* __restrict__ hw_key,   const float* __restrict__ hb_key,
    const float* __restrict__ hw_vol,   const float* __restrict__ hb_vol,
    const float* __restrict__ hw_conf,  const float* __restrict__ hb_conf,
    float* __restrict__ out)
{
    __shared__ float t1s[256], t2s[64], igs[32];
    int b = blockIdx.x, tid = threadIdx.x;
#pragma unroll
    for (int i = 0; i < 4; ++i) t1s[tid + i * 64] = t1[b * 256 + tid + i * 64];
    __syncthreads();
    float acc = ib2[tid];
#pragma unroll 4
    for (int k = 0; k < 256; ++k) acc = fmaf(t1s[k], iw2[tid * 256 + k], acc);
    t2s[tid] = fmaxf(acc, 0.f);
    __syncthreads();
    if (tid < 32) {
        float a2 = ib3[tid];
#pragma unroll 4
        for (int k = 0; k < 64; ++k) a2 = fmaf(t2s[k], iw3[tid * 64 + k], a2);
        igs[tid] = tanhft(a2);
    }
    __syncthreads();
    if (tid < 15) {
        const float* w; const float* bb; int j, off;
        if (tid < 3)        { w = hw_trend; bb = hb_trend; j = tid;     off = 0; }
        else if (tid < 9)   { w = hw_pat;   bb = hb_pat;   j = tid - 3; off = 3; }
        else if (tid < 13)  { w = hw_key;   bb = hb_key;   j = tid - 9; off = 9; }
        else if (tid == 13) { w = hw_vol;   bb = hb_vol;   j = 0;       off = 13; }
        else                { w = hw_conf;  bb = hb_conf;  j = 0;       off = 14; }
        float a3 = bb[j];
#pragma unroll
        for (int k = 0; k < 32; ++k) a3 = fmaf(igs[k], w[j * 32 + k], a3);
        out[b * 20 + off + j] = a3;
        if (tid == 14) out[b * 20 + 15] = sigf(a3);
    }
}

// ---------------------------------------------------------------------------
// group means of a -> out[:, 16:20]
// ---------------------------------------------------------------------------
__global__ __launch_bounds__(256) void means_kernel(
    const float* __restrict__ amat, float* __restrict__ out)
{
    __shared__ float red[256];
    int b = blockIdx.x, tid = threadIdx.x;
    float parts[4] = {0.f, 0.f, 0.f, 0.f};
    for (int n = tid; n < 2500; n += 256) {
        float v = amat[b * 2500 + n];
        if (n < 800)       parts[0] += v;
        else if (n < 1500) parts[1] += v;
        else if (n < 2100) parts[2] += v;
        else               parts[3] += v;
    }
    const float inv[4] = {1.f / 800.f, 1.f / 700.f, 1.f / 600.f, 1.f / 400.f};
#pragma unroll
    for (int g = 0; g < 4; ++g) {
        red[tid] = parts[g];
        __syncthreads();
        for (int s = 128; s > 0; s >>= 1) {
            if (tid < s) red[tid] += red[tid + s];
            __syncthreads();
        }
        if (tid == 0) out[b * 20 + 16 + g] = red[0] * inv[g];
        __syncthreads();
    }
}

// ---------------------------------------------------------------------------
extern "C" void kernel_launch(void* const* d_in, const int* in_sizes, int n_in,
                              void* d_out, int out_size, void* d_ws, size_t ws_size,
                              hipStream_t stream)
{
    const float* x        = (const float*)d_in[0];
    const int*   conn_idx = (const int*)  d_in[1];
    const float* w_ih0    = (const float*)d_in[2];
    const float* w_hh0    = (const float*)d_in[3];
    const float* b_ih0    = (const float*)d_in[4];
    const float* b_hh0    = (const float*)d_in[5];
    const float* w_ih1    = (const float*)d_in[6];
    const float* w_hh1    = (const float*)d_in[7];
    const float* b_ih1    = (const float*)d_in[8];
    const float* b_hh1    = (const float*)d_in[9];
    const float* pw1      = (const float*)d_in[10];
    const float* pb1      = (const float*)d_in[11];
    const float* pw2      = (const float*)d_in[12];
    const float* pb2      = (const float*)d_in[13];
    const float* conn_w   = (const float*)d_in[14];
    const float* sens     = (const float*)d_in[15];
    const float* thr      = (const float*)d_in[16];
    const float* iw1      = (const float*)d_in[17];
    const float* ib1      = (const float*)d_in[18];
    const float* iw2      = (const float*)d_in[19];
    const float* ib2      = (const float*)d_in[20];
    const float* iw3      = (const float*)d_in[21];
    const float* ib3      = (const float*)d_in[22];
    const float* hw_trend = (const float*)d_in[23];
    const float* hb_trend = (const float*)d_in[24];
    const float* hw_pat   = (const float*)d_in[25];
    const float* hb_pat   = (const float*)d_in[26];
    const float* hw_key   = (const float*)d_in[27];
    const float* hb_key   = (const float*)d_in[28];
    const float* hw_vol   = (const float*)d_in[29];
    const float* hb_vol   = (const float*)d_in[30];
    const float* hw_conf  = (const float*)d_in[31];
    const float* hb_conf  = (const float*)d_in[32];
    float* out = (float*)d_out;
    float* ws  = (float*)d_ws;

    // ws layout (float slots)
    unsigned int* wph0  = (unsigned int*)(ws);           // 32768
    unsigned int* wph1i = (unsigned int*)(ws + 32768);   // 32768
    unsigned int* wph1h = (unsigned int*)(ws + 65536);   // 32768
    float* wt_ih0 = ws + 98304;    // 2560
    float* bias0  = ws + 100864;   // 512
    float* bias1  = ws + 101376;   // 512
    float* h2     = ws + 101888;   // 131072
    float* base_  = ws + 232960;   // 32768
    float* weffT  = ws + 265728;   // 80000
    float* t1     = ws + 345728;   // 262144
    float* amat   = ws + 607872;   // 2560000

    prep_kernel<<<140, 256, 0, stream>>>(w_hh0, w_ih1, w_hh1, w_ih0,
                                         b_ih0, b_hh0, b_ih1, b_hh1,
                                         wph0, wph1i, wph1h, wt_ih0, bias0, bias1);
    lstm_kernel<<<256, 512, 0, stream>>>(x, wph0, wt_ih0, bias0, wph1i, wph1h, bias1, h2);
    phase2_kernel<<<1024, 64, 0, stream>>>(h2, pw1, pb1, pw2, pb2, base_);
    weff_kernel<<<20, 128, 0, stream>>>(conn_idx, conn_w, weffT);
    za_kernel<<<640, 256, 0, stream>>>(base_, weffT, sens, thr, amat);
    gemm_iw1_kernel<<<dim3(8, 32), 256, 0, stream>>>(amat, iw1, ib1, t1);
    final_kernel<<<1024, 64, 0, stream>>>(t1, iw2, ib2, iw3, ib3,
                                          hw_trend, hb_trend, hw_pat, hb_pat,
                                          hw_key, hb_key, hw_vol, hb_vol,
                                          hw_conf, hb_conf, out);
    means_kernel<<<1024, 256, 0, stream>>>(amat, out);
}

// Round 5
// 597.832 us; speedup vs baseline: 2.4919x; 1.2730x over previous
//
#include <hip/hip_runtime.h>
#include <hip/hip_bf16.h>
#include <math.h>

#define DEV __device__ __forceinline__

typedef short short8 __attribute__((ext_vector_type(8)));
typedef float f32x4  __attribute__((ext_vector_type(4)));

DEV float sigf(float x)   { return 1.0f / (1.0f + __expf(-x)); }
DEV float tanhft(float x) { return 1.0f - 2.0f / (__expf(2.0f * x) + 1.0f); }

// float -> bf16 (round to nearest even), as raw u16
DEV unsigned short f2bf(float f) {
    unsigned int u = __float_as_uint(f);
    unsigned int r = (u + 0x7FFFu + ((u >> 16) & 1u)) >> 16;
    return (unsigned short)r;
}

// LDS-only barrier: drain LDS ops but leave global loads (vmcnt) in flight.
// All cross-thread communication in lstm_kernel goes through LDS (round-2
// verified pattern).
DEV void bar_lds() {
    asm volatile("s_waitcnt lgkmcnt(0)" ::: "memory");
    __builtin_amdgcn_s_barrier();
}

// ---------------------------------------------------------------------------
// prep: convert the three recurrent weight matrices to bf16 (natural
// [col][128] layout — MFMA B-fragments read 16B of contiguous k per lane)
// and sum biases.
// ---------------------------------------------------------------------------
__global__ __launch_bounds__(256) void prep_kernel(
    const float* __restrict__ w_hh0, const float* __restrict__ w_ih1,
    const float* __restrict__ w_hh1,
    const float* __restrict__ b_ih0, const float* __restrict__ b_hh0,
    const float* __restrict__ b_ih1, const float* __restrict__ b_hh1,
    unsigned short* __restrict__ whh0h, unsigned short* __restrict__ wih1h,
    unsigned short* __restrict__ whh1h,
    float* __restrict__ bias0, float* __restrict__ bias1)
{
    int i = blockIdx.x * 256 + threadIdx.x;
    if (i < 65536) {
        whh0h[i] = f2bf(w_hh0[i]);
        wih1h[i] = f2bf(w_ih1[i]);
        whh1h[i] = f2bf(w_hh1[i]);
    } else if (i < 66048) {
        int c = i - 65536;
        bias0[c] = b_ih0[c] + b_hh0[c];
        bias1[c] = b_ih1[c] + b_hh1[c];
    }
}

// ---------------------------------------------------------------------------
// MFMA LSTM (bf16): 64 blocks x 512 threads, 16 batch rows/block, both
// layers, 60 steps. mfma_f32_16x16x32_bf16 (the m91 end-to-end-verified
// instruction), M=16(batch) x N=512(gates) x K=128.
// Wave w takes N-tiles {16w, 16w+128, 16w+256, 16w+384} => each lane's 16
// accumulators hold all 4 gates of hidden unit j=16w+(lane&15) for rows
// m=(lane>>4)*4+r  => LSTM update fully in-register.
// w_hh0 + w_ih1 B-fragments register-resident across all 60 steps;
// w_hh1 streamed from L2 each step, prefetched across the lgkm-only barrier.
// Biases loaded straight from global into registers (race-free).
// ---------------------------------------------------------------------------
__global__ __launch_bounds__(512, 2) void lstm_kernel(
    const float* __restrict__ x,
    const unsigned short* __restrict__ whh0,
    const unsigned short* __restrict__ wih1,
    const unsigned short* __restrict__ whh1,
    const float* __restrict__ wih0,
    const float* __restrict__ bias0, const float* __restrict__ bias1,
    float* __restrict__ h2out)
{
    __shared__ __align__(16) float          xs[16 * 301];
    __shared__ __align__(16) unsigned short h0s[2][16][136];
    __shared__ __align__(16) unsigned short h1s[2][16][136];
    __shared__ float wih0s[2560];

    const int tid = threadIdx.x;
    const int b0  = blockIdx.x * 16;
    const int l15 = tid & 15;          // MFMA col lane index (and A-row)
    const int q   = (tid >> 4) & 3;    // lane quad
    const int w   = tid >> 6;          // wave 0..7
    const int j   = w * 16 + l15;      // hidden unit owned in C/D
    const int q8  = q * 8;
    const int m0  = q * 4;

    // ---- stage x, w_ih0; zero h buffers
    for (int i = tid; i < 4800; i += 512) {
        int m = i / 300, kk = i - m * 300;
        xs[m * 301 + kk] = x[(b0 + m) * 300 + kk];
    }
    for (int i = tid; i < 2560; i += 512) wih0s[i] = wih0[i];
    for (int i = tid; i < 2176; i += 512) {
        ((unsigned int*)h0s)[i] = 0u;
        ((unsigned int*)h1s)[i] = 0u;
    }

    // ---- per-lane biases straight from global (race-free)
    const float bg0[4] = {bias0[j], bias0[128 + j], bias0[256 + j], bias0[384 + j]};
    const float bg1[4] = {bias1[j], bias1[128 + j], bias1[256 + j], bias1[384 + j]};

    // ---- resident B-fragments: w_hh0 (layer0 recurrent), w_ih1 (layer1 input)
    short8 bh0[4][4], b1i[4][4];
#pragma unroll
    for (int g = 0; g < 4; ++g)
#pragma unroll
        for (int kc = 0; kc < 4; ++kc) {
            int off = (g * 128 + j) * 128 + kc * 32 + q8;
            bh0[g][kc] = *(const short8*)(whh0 + off);
            b1i[g][kc] = *(const short8*)(wih1 + off);
        }

    float c0[4] = {0.f, 0.f, 0.f, 0.f};
    float c1[4] = {0.f, 0.f, 0.f, 0.f};
    float hlast[4] = {0.f, 0.f, 0.f, 0.f};

    __syncthreads();

    const unsigned short* wsb = whh1 + j * 128 + q8;  // per-lane stream base

    for (int t = 0; t < 60; ++t) {
        const int p = t & 1;

        // ---- prefetch streamed w_hh1, first half (kc=0,1)
        short8 wsv[4][4];
#pragma unroll
        for (int g = 0; g < 4; ++g) {
            wsv[g][0] = *(const short8*)(wsb + g * 16384);
            wsv[g][1] = *(const short8*)(wsb + g * 16384 + 32);
        }

        // ---- layer 0: acc = bias; A = h0[p]; MFMA vs resident w_hh0
        f32x4 acc[4];
#pragma unroll
        for (int g = 0; g < 4; ++g) {
            float b = bg0[g];
            acc[g] = (f32x4){b, b, b, b};
        }
        short8 af[4];
#pragma unroll
        for (int kc = 0; kc < 4; ++kc)
            af[kc] = *(const short8*)&h0s[p][l15][kc * 32 + q8];
#pragma unroll
        for (int kc = 0; kc < 4; ++kc)
#pragma unroll
            for (int g = 0; g < 4; ++g)
                acc[g] = __builtin_amdgcn_mfma_f32_16x16x32_bf16(af[kc], bh0[g][kc], acc[g], 0, 0, 0);

        // ---- prefetch streamed w_hh1, second half (kc=2,3)
#pragma unroll
        for (int g = 0; g < 4; ++g) {
            wsv[g][2] = *(const short8*)(wsb + g * 16384 + 64);
            wsv[g][3] = *(const short8*)(wsb + g * 16384 + 96);
        }

        // ---- x-part: acc[g][r] += x[m][t,:] . w_ih0[gate col,:]  (fp32)
#pragma unroll
        for (int r = 0; r < 4; ++r) {
            const float* xr = &xs[(m0 + r) * 301 + t * 5];
            float x0 = xr[0], x1 = xr[1], x2 = xr[2], x3 = xr[3], x4 = xr[4];
#pragma unroll
            for (int g = 0; g < 4; ++g) {
                const float* wr = &wih0s[(g * 128 + j) * 5];
                float s = fmaf(x0, wr[0], acc[g][r]);
                s = fmaf(x1, wr[1], s);
                s = fmaf(x2, wr[2], s);
                s = fmaf(x3, wr[3], s);
                acc[g][r] = fmaf(x4, wr[4], s);
            }
        }

        // ---- layer 0 update (in-register), write new h0 (bf16)
#pragma unroll
        for (int r = 0; r < 4; ++r) {
            float gi = acc[0][r], gf = acc[1][r], gg = acc[2][r], go = acc[3][r];
            c0[r] = sigf(gf) * c0[r] + sigf(gi) * tanhft(gg);
            float h = sigf(go) * tanhft(c0[r]);
            h0s[1 - p][m0 + r][j] = f2bf(h);
        }
        bar_lds();

        // ---- layer 1: acc = bias; h0new @ w_ih1^T + h1 @ w_hh1^T
#pragma unroll
        for (int g = 0; g < 4; ++g) {
            float b = bg1[g];
            acc[g] = (f32x4){b, b, b, b};
        }
#pragma unroll
        for (int kc = 0; kc < 4; ++kc)
            af[kc] = *(const short8*)&h0s[1 - p][l15][kc * 32 + q8];
#pragma unroll
        for (int kc = 0; kc < 4; ++kc)
#pragma unroll
            for (int g = 0; g < 4; ++g)
                acc[g] = __builtin_amdgcn_mfma_f32_16x16x32_bf16(af[kc], b1i[g][kc], acc[g], 0, 0, 0);
#pragma unroll
        for (int kc = 0; kc < 4; ++kc)
            af[kc] = *(const short8*)&h1s[p][l15][kc * 32 + q8];
#pragma unroll
        for (int kc = 0; kc < 4; ++kc)
#pragma unroll
            for (int g = 0; g < 4; ++g)
                acc[g] = __builtin_amdgcn_mfma_f32_16x16x32_bf16(af[kc], wsv[g][kc], acc[g], 0, 0, 0);

        // ---- layer 1 update, write new h1; keep last h in regs
#pragma unroll
        for (int r = 0; r < 4; ++r) {
            float gi = acc[0][r], gf = acc[1][r], gg = acc[2][r], go = acc[3][r];
            c1[r] = sigf(gf) * c1[r] + sigf(gi) * tanhft(gg);
            float h = sigf(go) * tanhft(c1[r]);
            h1s[1 - p][m0 + r][j] = f2bf(h);
            hlast[r] = h;
        }
        bar_lds();
    }

#pragma unroll
    for (int r = 0; r < 4; ++r)
        h2out[(b0 + m0 + r) * 128 + j] = hlast[r];
}

// ---------------------------------------------------------------------------
// base = tanh(relu(h2 @ pw1^T + pb1) @ pw2^T + pb2)   (1024 x 32)
// ROUND-2 VERIFIED VERSION (verbatim).
// ---------------------------------------------------------------------------
__global__ __launch_bounds__(64) void phase2_kernel(
    const float* __restrict__ h2, const float* __restrict__ pw1,
    const float* __restrict__ pb1, const float* __restrict__ pw2,
    const float* __restrict__ pb2, float* __restrict__ base)
{
    __shared__ float hs[128], p1[64];
    int b = blockIdx.x, tid = threadIdx.x;
    hs[tid] = h2[b * 128 + tid];
    hs[tid + 64] = h2[b * 128 + 64 + tid];
    __syncthreads();
    float acc = pb1[tid];
#pragma unroll 4
    for (int k = 0; k < 128; ++k) acc = fmaf(hs[k], pw1[tid * 128 + k], acc);
    p1[tid] = fmaxf(acc, 0.f);
    __syncthreads();
    if (tid < 32) {
        float a2 = pb2[tid];
#pragma unroll 4
        for (int k = 0; k < 64; ++k) a2 = fmaf(p1[k], pw2[tid * 64 + k], a2);
        base[b * 32 + tid] = tanhft(a2);
    }
}

// ---------------------------------------------------------------------------
// W_eff^T[j][n] = sum_{k: conn_idx[n,k]%32==j} conn_w[n,k]
// ---------------------------------------------------------------------------
__global__ __launch_bounds__(128) void weff_kernel(
    const int* __restrict__ conn_idx, const float* __restrict__ conn_w,
    float* __restrict__ weffT)
{
    __shared__ float s[128 * 33];
    int tid = threadIdx.x;
    int n = blockIdx.x * 128 + tid;
    float* sr = &s[tid * 33];
#pragma unroll
    for (int j = 0; j < 32; ++j) sr[j] = 0.f;
    if (n < 2500) {
        for (int k = 0; k < 50; ++k) {
            int idx = conn_idx[n * 50 + k];
            sr[idx & 31] += conn_w[n * 50 + k];
        }
        for (int j = 0; j < 32; ++j) weffT[j * 2500 + n] = sr[j];
    }
}

// ---------------------------------------------------------------------------
// z = (base @ W_eff^T) * sens; a = per-group activation. a stored [b][n].
// ---------------------------------------------------------------------------
__global__ __launch_bounds__(256) void za_kernel(
    const float* __restrict__ base, const float* __restrict__ weffT,
    const float* __restrict__ sens, const float* __restrict__ thr,
    float* __restrict__ amat)
{
    __shared__ float bs[16][32];
    int tid = threadIdx.x;
    int bb = blockIdx.x / 10, nb = blockIdx.x % 10;
    int n = nb * 256 + tid;
    bool nv = n < 2500;
    int nn = nv ? n : 0;
    for (int i = tid; i < 512; i += 256) bs[i >> 5][i & 31] = base[bb * 512 + i];
    __syncthreads();
    float w[32];
#pragma unroll
    for (int j = 0; j < 32; ++j) w[j] = weffT[j * 2500 + nn];
    float sn = sens[nn], tn = thr[nn];
    int g = (n < 800) ? 0 : (n < 1500) ? 1 : (n < 2100) ? 2 : 3;
#pragma unroll 2
    for (int r = 0; r < 16; ++r) {
        float z = 0.f;
#pragma unroll
        for (int j = 0; j < 32; ++j) z = fmaf(bs[r][j], w[j], z);
        z *= sn;
        float av;
        if (g == 0)      av = sigf(z - tn);
        else if (g == 1) av = tanhft(z);
        else if (g == 2) av = fmaxf(z - tn, 0.f);
        else             av = sigf(z);
        if (nv) amat[(bb * 16 + r) * 2500 + n] = av;
    }
}

// ---------------------------------------------------------------------------
// t1 = relu(a @ iw1^T + ib1): M=1024 N=256 K=2500.
// ---------------------------------------------------------------------------
__global__ __launch_bounds__(256) void gemm_iw1_kernel(
    const float* __restrict__ amat, const float* __restrict__ iw1,
    const float* __restrict__ ib1, float* __restrict__ t1)
{
    __shared__ float sa[32][65], sw[32][65];
    int tid = threadIdx.x;
    int tx = tid & 15, ty = tid >> 4;
    int col0 = blockIdx.x * 32, row0 = blockIdx.y * 32;
    int kk = tid & 63, rr = tid >> 6;
    float acc00 = 0, acc01 = 0, acc10 = 0, acc11 = 0;
    for (int k0 = 0; k0 < 2500; k0 += 64) {
        int k = k0 + kk;
        bool kv = k < 2500;
#pragma unroll
        for (int p = 0; p < 8; ++p) {
            int r = rr + p * 4;
            sa[r][kk] = kv ? amat[(row0 + r) * 2500 + k] : 0.f;
            sw[r][kk] = kv ? iw1[(col0 + r) * 2500 + k] : 0.f;
        }
        __syncthreads();
#pragma unroll 8
        for (int k2 = 0; k2 < 64; ++k2) {
            float a0 = sa[ty * 2][k2],     a1 = sa[ty * 2 + 1][k2];
            float w0 = sw[tx * 2][k2],     w1 = sw[tx * 2 + 1][k2];
            acc00 = fmaf(a0, w0, acc00);
            acc01 = fmaf(a0, w1, acc01);
            acc10 = fmaf(a1, w0, acc10);
            acc11 = fmaf(a1, w1, acc11);
        }
        __syncthreads();
    }
    int row = row0 + ty * 2, col = col0 + tx * 2;
    float b0v = ib1[col], b1v = ib1[col + 1];
    t1[row * 256 + col]           = fmaxf(acc00 + b0v, 0.f);
    t1[row * 256 + col + 1]       = fmaxf(acc01 + b1v, 0.f);
    t1[(row + 1) * 256 + col]     = fmaxf(acc10 + b0v, 0.f);
    t1[(row + 1) * 256 + col + 1] = fmaxf(acc11 + b1v, 0.f);
}

// ---------------------------------------------------------------------------
// t2 = relu(t1@iw2^T+ib2); integ = tanh(t2@iw3^T+ib3); 5 heads + overall.
// ROUND-2 VERIFIED VERSION (verbatim).
// out row: [trend 0:3 | pat 3:9 | key 9:13 | vol 13 | conf 14 | overall 15 |
//           means 16:20]
// ---------------------------------------------------------------------------
__global__ __launch_bounds__(64) void final_kernel(
    const float* __restrict__ t1, const float* __restrict__ iw2,
    const float* __restrict__ ib2, const float* __restrict__ iw3,
    const float* __restrict__ ib3,
    const float* __restrict__ hw_trend, const float* __restrict__ hb_trend,
    const float* __restrict__ hw_pat,   const float* __restrict__ hb_pat,
    const float* __restrict__ hw_key,   const float* __restrict__ hb_key,
    const float* __restrict__ hw_vol,   const float* __restrict__ hb_vol,
    const float* __restrict__ hw_conf,  const float* __restrict__ hb_conf,
    float* __restrict__ out)
{
    __shared__ float t1s[256], t2s[64], igs[32];
    int b = blockIdx.x, tid = threadIdx.x;
#pragma unroll
    for (int i = 0; i < 4; ++i) t1s[tid + i * 64] = t1[b * 256 + tid + i * 64];
    __syncthreads();
    float acc = ib2[tid];
#pragma unroll 4
    for (int k = 0; k < 256; ++k) acc = fmaf(t1s[k], iw2[tid * 256 + k], acc);
    t2s[tid] = fmaxf(acc, 0.f);
    __syncthreads();
    if (tid < 32) {
        float a2 = ib3[tid];
#pragma unroll 4
        for (int k = 0; k < 64; ++k) a2 = fmaf(t2s[k], iw3[tid * 64 + k], a2);
        igs[tid] = tanhft(a2);
    }
    __syncthreads();
    if (tid < 15) {
        const float* w; const float* bb; int j, off;
        if (tid < 3)        { w = hw_trend; bb = hb_trend; j = tid;     off = 0; }
        else if (tid < 9)   { w = hw_pat;   bb = hb_pat;   j = tid - 3; off = 3; }
        else if (tid < 13)  { w = hw_key;   bb = hb_key;   j = tid - 9; off = 9; }
        else if (tid == 13) { w = hw_vol;   bb = hb_vol;   j = 0;       off = 13; }
        else                { w = hw_conf;  bb = hb_conf;  j = 0;       off = 14; }
        float a3 = bb[j];
#pragma unroll
        for (int k = 0; k < 32; ++k) a3 = fmaf(igs[k], w[j * 32 + k], a3);
        out[b * 20 + off + j] = a3;
        if (tid == 14) out[b * 20 + 15] = sigf(a3);
    }
}

// ---------------------------------------------------------------------------
// group means of a -> out[:, 16:20]
// ---------------------------------------------------------------------------
__global__ __launch_bounds__(256) void means_kernel(
    const float* __restrict__ amat, float* __restrict__ out)
{
    __shared__ float red[256];
    int b = blockIdx.x, tid = threadIdx.x;
    float parts[4] = {0.f, 0.f, 0.f, 0.f};
    for (int n = tid; n < 2500; n += 256) {
        float v = amat[b * 2500 + n];
        if (n < 800)       parts[0] += v;
        else if (n < 1500) parts[1] += v;
        else if (n < 2100) parts[2] += v;
        else               parts[3] += v;
    }
    const float inv[4] = {1.f / 800.f, 1.f / 700.f, 1.f / 600.f, 1.f / 400.f};
#pragma unroll
    for (int g = 0; g < 4; ++g) {
        red[tid] = parts[g];
        __syncthreads();
        for (int s = 128; s > 0; s >>= 1) {
            if (tid < s) red[tid] += red[tid + s];
            __syncthreads();
        }
        if (tid == 0) out[b * 20 + 16 + g] = red[0] * inv[g];
        __syncthreads();
    }
}

// ---------------------------------------------------------------------------
extern "C" void kernel_launch(void* const* d_in, const int* in_sizes, int n_in,
                              void* d_out, int out_size, void* d_ws, size_t ws_size,
                              hipStream_t stream)
{
    const float* x        = (const float*)d_in[0];
    const int*   conn_idx = (const int*)  d_in[1];
    const float* w_ih0    = (const float*)d_in[2];
    const float* w_hh0    = (const float*)d_in[3];
    const float* b_ih0    = (const float*)d_in[4];
    const float* b_hh0    = (const float*)d_in[5];
    const float* w_ih1    = (const float*)d_in[6];
    const float* w_hh1    = (const float*)d_in[7];
    const float* b_ih1    = (const float*)d_in[8];
    const float* b_hh1    = (const float*)d_in[9];
    const float* pw1      = (const float*)d_in[10];
    const float* pb1      = (const float*)d_in[11];
    const float* pw2      = (const float*)d_in[12];
    const float* pb2      = (const float*)d_in[13];
    const float* conn_w   = (const float*)d_in[14];
    const float* sens     = (const float*)d_in[15];
    const float* thr      = (const float*)d_in[16];
    const float* iw1      = (const float*)d_in[17];
    const float* ib1      = (const float*)d_in[18];
    const float* iw2      = (const float*)d_in[19];
    const float* ib2      = (const float*)d_in[20];
    const float* iw3      = (const float*)d_in[21];
    const float* ib3      = (const float*)d_in[22];
    const float* hw_trend = (const float*)d_in[23];
    const float* hb_trend = (const float*)d_in[24];
    const float* hw_pat   = (const float*)d_in[25];
    const float* hb_pat   = (const float*)d_in[26];
    const float* hw_key   = (const float*)d_in[27];
    const float* hb_key   = (const float*)d_in[28];
    const float* hw_vol   = (const float*)d_in[29];
    const float* hb_vol   = (const float*)d_in[30];
    const float* hw_conf  = (const float*)d_in[31];
    const float* hb_conf  = (const float*)d_in[32];
    float* out = (float*)d_out;
    float* ws  = (float*)d_ws;

    // ws layout (float slots)
    unsigned short* whh0h = (unsigned short*)(ws);           // 65536 u16 = 32768 f
    unsigned short* wih1h = (unsigned short*)(ws + 32768);   // 32768 f
    unsigned short* whh1h = (unsigned short*)(ws + 65536);   // 32768 f
    float* bias0  = ws + 98304;   // 512
    float* bias1  = ws + 98816;   // 512
    float* h2     = ws + 99328;   // 131072
    float* base_  = ws + 230400;  // 32768
    float* weffT  = ws + 263168;  // 80000
    float* t1     = ws + 343168;  // 262144
    float* amat   = ws + 605312;  // 2560000

    prep_kernel<<<258, 256, 0, stream>>>(w_hh0, w_ih1, w_hh1,
                                         b_ih0, b_hh0, b_ih1, b_hh1,
                                         whh0h, wih1h, whh1h, bias0, bias1);
    lstm_kernel<<<64, 512, 0, stream>>>(x, whh0h, wih1h, whh1h, w_ih0,
                                        bias0, bias1, h2);
    phase2_kernel<<<1024, 64, 0, stream>>>(h2, pw1, pb1, pw2, pb2, base_);
    weff_kernel<<<20, 128, 0, stream>>>(conn_idx, conn_w, weffT);
    za_kernel<<<640, 256, 0, stream>>>(base_, weffT, sens, thr, amat);
    gemm_iw1_kernel<<<dim3(8, 32), 256, 0, stream>>>(amat, iw1, ib1, t1);
    final_kernel<<<1024, 64, 0, stream>>>(t1, iw2, ib2, iw3, ib3,
                                          hw_trend, hb_trend, hw_pat, hb_pat,
                                          hw_key, hb_key, hw_vol, hb_vol,
                                          hw_conf, hb_conf, out);
    means_kernel<<<1024, 256, 0, stream>>>(amat, out);
}

// Round 6
// 339.634 us; speedup vs baseline: 4.3863x; 1.7602x over previous
//
#include <hip/hip_runtime.h>
#include <hip/hip_bf16.h>
#include <math.h>

#define DEV __device__ __forceinline__

typedef short short8 __attribute__((ext_vector_type(8)));
typedef float f32x4  __attribute__((ext_vector_type(4)));

DEV float sigf(float x)   { return 1.0f / (1.0f + __expf(-x)); }
DEV float tanhft(float x) { return 1.0f - 2.0f / (__expf(2.0f * x) + 1.0f); }

// float -> bf16 (round to nearest even), as raw u16
DEV unsigned short f2bf(float f) {
    unsigned int u = __float_as_uint(f);
    unsigned int r = (u + 0x7FFFu + ((u >> 16) & 1u)) >> 16;
    return (unsigned short)r;
}
DEV float bf2f(unsigned short u) {
    return __uint_as_float(((unsigned int)u) << 16);
}

// LDS-only barrier: drain LDS ops but leave global loads (vmcnt) in flight.
DEV void bar_lds() {
    asm volatile("s_waitcnt lgkmcnt(0)" ::: "memory");
    __builtin_amdgcn_s_barrier();
}

// ---------------------------------------------------------------------------
// prep: recurrent weights -> bf16 (natural [col][128] layout), bias sums.
// ---------------------------------------------------------------------------
__global__ __launch_bounds__(256) void prep_kernel(
    const float* __restrict__ w_hh0, const float* __restrict__ w_ih1,
    const float* __restrict__ w_hh1,
    const float* __restrict__ b_ih0, const float* __restrict__ b_hh0,
    const float* __restrict__ b_ih1, const float* __restrict__ b_hh1,
    unsigned short* __restrict__ whh0h, unsigned short* __restrict__ wih1h,
    unsigned short* __restrict__ whh1h,
    float* __restrict__ bias0, float* __restrict__ bias1)
{
    int i = blockIdx.x * 256 + threadIdx.x;
    if (i < 65536) {
        whh0h[i] = f2bf(w_hh0[i]);
        wih1h[i] = f2bf(w_ih1[i]);
        whh1h[i] = f2bf(w_hh1[i]);
    } else if (i < 66048) {
        int c = i - 65536;
        bias0[c] = b_ih0[c] + b_hh0[c];
        bias1[c] = b_ih1[c] + b_hh1[c];
    }
}

// prep iw1 -> bf16 [256][2528], zero-padded K 2500..2527
__global__ __launch_bounds__(256) void prep_iw1_kernel(
    const float* __restrict__ iw1, unsigned short* __restrict__ iw1b)
{
    int i = blockIdx.x * 256 + threadIdx.x;
    if (i < 256 * 2528) {
        int row = i / 2528, k = i - row * 2528;
        iw1b[i] = (k < 2500) ? f2bf(iw1[row * 2500 + k]) : (unsigned short)0;
    }
}

// ---------------------------------------------------------------------------
// MFMA LSTM: 256 blocks x 512 threads, 4 batch rows/block, both layers,
// 60 steps. mfma_f32_16x16x32_bf16, M=16 (rows 4..15 permanently zero),
// N=512 gates, K=128. MFMA dataflow identical to the R5-verified kernel.
// Update phase redistributed via LDS gbuf: 1 (row,hidden) element/thread
// (20 transcendentals/step vs 80). x-part + bias folded into the update.
// w_hh0 + w_ih1 register-resident; w_hh1 streamed from L2, prefetched
// across lgkm-only barriers. 3 barriers/step (dual gbuf removes the 4th).
// ---------------------------------------------------------------------------
__global__ __launch_bounds__(512, 2) void lstm_kernel(
    const float* __restrict__ x,
    const unsigned short* __restrict__ whh0,
    const unsigned short* __restrict__ wih1,
    const unsigned short* __restrict__ whh1,
    const float* __restrict__ wih0,
    const float* __restrict__ bias0, const float* __restrict__ bias1,
    float* __restrict__ h2out)
{
    __shared__ __align__(16) float          xs[4][304];
    __shared__ __align__(16) unsigned short h0s[2][16][136];
    __shared__ __align__(16) unsigned short h1s[2][16][136];
    __shared__ float gbuf0[4][512];
    __shared__ float gbuf1[4][512];
    __shared__ float wih0s[2560];

    const int tid = threadIdx.x;
    const int b0  = blockIdx.x * 4;
    const int l15 = tid & 15;          // MFMA A-row / C-col lane index
    const int q   = (tid >> 4) & 3;    // lane quad
    const int w   = tid >> 6;          // wave 0..7
    const int j   = w * 16 + l15;      // gate column owned in C/D
    const int q8  = q * 8;
    const int r_u = tid >> 7;          // update role: row 0..3
    const int j_u = tid & 127;         // update role: hidden unit

    // ---- stage x (4 rows), w_ih0; zero h buffers (rows 4..15 stay zero)
    for (int i = tid; i < 1200; i += 512) {
        int m = i / 300, kk = i - m * 300;
        xs[m][kk] = x[(b0 + m) * 300 + kk];
    }
    for (int i = tid; i < 2560; i += 512) wih0s[i] = wih0[i];
    for (int i = tid; i < 2176; i += 512) {
        ((unsigned int*)h0s)[i] = 0u;
        ((unsigned int*)h1s)[i] = 0u;
    }

    // ---- update-role biases (coalesced global loads, race-free)
    const float ub0[4] = {bias0[j_u], bias0[128 + j_u], bias0[256 + j_u], bias0[384 + j_u]};
    const float ub1[4] = {bias1[j_u], bias1[128 + j_u], bias1[256 + j_u], bias1[384 + j_u]};

    // ---- resident B-fragments: w_hh0, w_ih1
    short8 bh0[4][4], b1i[4][4];
#pragma unroll
    for (int g = 0; g < 4; ++g)
#pragma unroll
        for (int kc = 0; kc < 4; ++kc) {
            int off = (g * 128 + j) * 128 + kc * 32 + q8;
            bh0[g][kc] = *(const short8*)(whh0 + off);
            b1i[g][kc] = *(const short8*)(wih1 + off);
        }

    float c0 = 0.f, c1 = 0.f, hl = 0.f;
    __syncthreads();

    const unsigned short* wsb = whh1 + j * 128 + q8;  // per-lane stream base

    for (int t = 0; t < 60; ++t) {
        const int p = t & 1;

        // ---- prefetch streamed w_hh1, first half
        short8 wsv[4][4];
#pragma unroll
        for (int g = 0; g < 4; ++g) {
            wsv[g][0] = *(const short8*)(wsb + g * 16384);
            wsv[g][1] = *(const short8*)(wsb + g * 16384 + 32);
        }

        // ---- layer 0 MFMA: h0[p] @ w_hh0^T  (C starts at 0)
        f32x4 acc[4];
#pragma unroll
        for (int g = 0; g < 4; ++g) acc[g] = (f32x4){0.f, 0.f, 0.f, 0.f};
        short8 af[4];
#pragma unroll
        for (int kc = 0; kc < 4; ++kc)
            af[kc] = *(const short8*)&h0s[p][l15][kc * 32 + q8];
#pragma unroll
        for (int kc = 0; kc < 4; ++kc)
#pragma unroll
            for (int g = 0; g < 4; ++g)
                acc[g] = __builtin_amdgcn_mfma_f32_16x16x32_bf16(af[kc], bh0[g][kc], acc[g], 0, 0, 0);

        // ---- prefetch streamed w_hh1, second half
#pragma unroll
        for (int g = 0; g < 4; ++g) {
            wsv[g][2] = *(const short8*)(wsb + g * 16384 + 64);
            wsv[g][3] = *(const short8*)(wsb + g * 16384 + 96);
        }

        // q==0 lanes hold valid C rows 0..3 -> publish to gbuf0
        if (q == 0) {
#pragma unroll
            for (int g = 0; g < 4; ++g)
#pragma unroll
                for (int r = 0; r < 4; ++r)
                    gbuf0[r][g * 128 + j] = acc[g][r];
        }
        bar_lds();  // BAR1

        // ---- layer 0 update: 1 element/thread (row r_u, unit j_u)
        {
            const float* xr = &xs[r_u][t * 5];
            float x0 = xr[0], x1 = xr[1], x2 = xr[2], x3 = xr[3], x4 = xr[4];
            float gv[4];
#pragma unroll
            for (int g = 0; g < 4; ++g) {
                const float* wr = &wih0s[(g * 128 + j_u) * 5];
                float s = gbuf0[r_u][g * 128 + j_u] + ub0[g];
                s = fmaf(x0, wr[0], s);
                s = fmaf(x1, wr[1], s);
                s = fmaf(x2, wr[2], s);
                s = fmaf(x3, wr[3], s);
                gv[g] = fmaf(x4, wr[4], s);
            }
            c0 = sigf(gv[1]) * c0 + sigf(gv[0]) * tanhft(gv[2]);
            float h = sigf(gv[3]) * tanhft(c0);
            h0s[1 - p][r_u][j_u] = f2bf(h);
        }
        bar_lds();  // BAR2

        // ---- layer 1 MFMA: h0new @ w_ih1^T + h1[p] @ w_hh1^T
#pragma unroll
        for (int g = 0; g < 4; ++g) acc[g] = (f32x4){0.f, 0.f, 0.f, 0.f};
#pragma unroll
        for (int kc = 0; kc < 4; ++kc)
            af[kc] = *(const short8*)&h0s[1 - p][l15][kc * 32 + q8];
#pragma unroll
        for (int kc = 0; kc < 4; ++kc)
#pragma unroll
            for (int g = 0; g < 4; ++g)
                acc[g] = __builtin_amdgcn_mfma_f32_16x16x32_bf16(af[kc], b1i[g][kc], acc[g], 0, 0, 0);
#pragma unroll
        for (int kc = 0; kc < 4; ++kc)
            af[kc] = *(const short8*)&h1s[p][l15][kc * 32 + q8];
#pragma unroll
        for (int kc = 0; kc < 4; ++kc)
#pragma unroll
            for (int g = 0; g < 4; ++g)
                acc[g] = __builtin_amdgcn_mfma_f32_16x16x32_bf16(af[kc], wsv[g][kc], acc[g], 0, 0, 0);

        if (q == 0) {
#pragma unroll
            for (int g = 0; g < 4; ++g)
#pragma unroll
                for (int r = 0; r < 4; ++r)
                    gbuf1[r][g * 128 + j] = acc[g][r];
        }
        bar_lds();  // BAR3

        // ---- layer 1 update (h1 write protected by BAR1/BAR2 of t+1;
        //      gbuf1 WAR protected by BAR2(t+1) before next L1 stores)
        {
            float gv[4];
#pragma unroll
            for (int g = 0; g < 4; ++g)
                gv[g] = gbuf1[r_u][g * 128 + j_u] + ub1[g];
            c1 = sigf(gv[1]) * c1 + sigf(gv[0]) * tanhft(gv[2]);
            float h = sigf(gv[3]) * tanhft(c1);
            h1s[1 - p][r_u][j_u] = f2bf(h);
            hl = h;
        }
        // no barrier here: next-iter BAR1 orders everything needed
    }

    h2out[(b0 + r_u) * 128 + j_u] = hl;
}

// ---------------------------------------------------------------------------
// base = tanh(relu(h2 @ pw1^T + pb1) @ pw2^T + pb2)  — R5-verified verbatim.
// ---------------------------------------------------------------------------
__global__ __launch_bounds__(64) void phase2_kernel(
    const float* __restrict__ h2, const float* __restrict__ pw1,
    const float* __restrict__ pb1, const float* __restrict__ pw2,
    const float* __restrict__ pb2, float* __restrict__ base)
{
    __shared__ float hs[128], p1[64];
    int b = blockIdx.x, tid = threadIdx.x;
    hs[tid] = h2[b * 128 + tid];
    hs[tid + 64] = h2[b * 128 + 64 + tid];
    __syncthreads();
    float acc = pb1[tid];
#pragma unroll 4
    for (int k = 0; k < 128; ++k) acc = fmaf(hs[k], pw1[tid * 128 + k], acc);
    p1[tid] = fmaxf(acc, 0.f);
    __syncthreads();
    if (tid < 32) {
        float a2 = pb2[tid];
#pragma unroll 4
        for (int k = 0; k < 64; ++k) a2 = fmaf(p1[k], pw2[tid * 64 + k], a2);
        base[b * 32 + tid] = tanhft(a2);
    }
}

// ---------------------------------------------------------------------------
// W_eff^T[j][n] = sum_{k: conn_idx[n,k]%32==j} conn_w[n,k]
// ---------------------------------------------------------------------------
__global__ __launch_bounds__(128) void weff_kernel(
    const int* __restrict__ conn_idx, const float* __restrict__ conn_w,
    float* __restrict__ weffT)
{
    __shared__ float s[128 * 33];
    int tid = threadIdx.x;
    int n = blockIdx.x * 128 + tid;
    float* sr = &s[tid * 33];
#pragma unroll
    for (int j = 0; j < 32; ++j) sr[j] = 0.f;
    if (n < 2500) {
        for (int k = 0; k < 50; ++k) {
            int idx = conn_idx[n * 50 + k];
            sr[idx & 31] += conn_w[n * 50 + k];
        }
        for (int j = 0; j < 32; ++j) weffT[j * 2500 + n] = sr[j];
    }
}

// ---------------------------------------------------------------------------
// z = (base @ W_eff^T)*sens; a = per-group activation. amat stored bf16
// [b][2528] (K-padded with zeros for the MFMA GEMM).
// ---------------------------------------------------------------------------
__global__ __launch_bounds__(256) void za_kernel(
    const float* __restrict__ base, const float* __restrict__ weffT,
    const float* __restrict__ sens, const float* __restrict__ thr,
    unsigned short* __restrict__ amat)
{
    __shared__ float bs[16][32];
    int tid = threadIdx.x;
    int bb = blockIdx.x / 10, nb = blockIdx.x % 10;
    int n = nb * 256 + tid;
    bool nv = n < 2500;
    bool pv = n < 2528;
    int nn = nv ? n : 0;
    for (int i = tid; i < 512; i += 256) bs[i >> 5][i & 31] = base[bb * 512 + i];
    __syncthreads();
    float w[32];
#pragma unroll
    for (int j = 0; j < 32; ++j) w[j] = weffT[j * 2500 + nn];
    float sn = sens[nn], tn = thr[nn];
    int g = (n < 800) ? 0 : (n < 1500) ? 1 : (n < 2100) ? 2 : 3;
#pragma unroll 2
    for (int r = 0; r < 16; ++r) {
        float z = 0.f;
#pragma unroll
        for (int j = 0; j < 32; ++j) z = fmaf(bs[r][j], w[j], z);
        z *= sn;
        float av;
        if (g == 0)      av = sigf(z - tn);
        else if (g == 1) av = tanhft(z);
        else if (g == 2) av = fmaxf(z - tn, 0.f);
        else             av = sigf(z);
        if (nv)      amat[(bb * 16 + r) * 2528 + n] = f2bf(av);
        else if (pv) amat[(bb * 16 + r) * 2528 + n] = 0;
    }
}

// ---------------------------------------------------------------------------
// t1 = relu(a @ iw1^T + ib1): M=1024 N=256 K=2528(padded), bf16 MFMA,
// register-fragment streaming (no LDS, no barriers). 128 thr = 2 waves,
// each wave an M=16 strip x N=64; grid (N/64=4, M/32=32) = 128 blocks.
// ---------------------------------------------------------------------------
__global__ __launch_bounds__(128) void gemm_iw1_kernel(
    const unsigned short* __restrict__ ab, const unsigned short* __restrict__ wb,
    const float* __restrict__ ib1, float* __restrict__ t1)
{
    const int tid = threadIdx.x;
    const int wv  = tid >> 6;
    const int l15 = tid & 15, q = (tid >> 4) & 3, q8 = q * 8;
    const int row0 = blockIdx.y * 32 + wv * 16;
    const int col0 = blockIdx.x * 64;

    const unsigned short* A = ab + (row0 + l15) * 2528 + q8;
    const unsigned short* B = wb + (col0 + l15) * 2528 + q8;

    short8 a = *(const short8*)A;
    short8 b[4];
#pragma unroll
    for (int nt = 0; nt < 4; ++nt) b[nt] = *(const short8*)(B + nt * 16 * 2528);

    f32x4 acc[4];
#pragma unroll
    for (int nt = 0; nt < 4; ++nt) acc[nt] = (f32x4){0.f, 0.f, 0.f, 0.f};

    for (int c = 0; c < 79; ++c) {
        int cn = (c < 78) ? c + 1 : 78;
        short8 an = *(const short8*)(A + cn * 32);
        short8 bn[4];
#pragma unroll
        for (int nt = 0; nt < 4; ++nt)
            bn[nt] = *(const short8*)(B + nt * 16 * 2528 + cn * 32);
#pragma unroll
        for (int nt = 0; nt < 4; ++nt)
            acc[nt] = __builtin_amdgcn_mfma_f32_16x16x32_bf16(a, b[nt], acc[nt], 0, 0, 0);
        a = an;
#pragma unroll
        for (int nt = 0; nt < 4; ++nt) b[nt] = bn[nt];
    }

#pragma unroll
    for (int nt = 0; nt < 4; ++nt) {
        int n = col0 + nt * 16 + l15;
        float bias = ib1[n];
#pragma unroll
        for (int i = 0; i < 4; ++i) {
            int row = row0 + q * 4 + i;
            t1[row * 256 + n] = fmaxf(acc[nt][i] + bias, 0.f);
        }
    }
}

// ---------------------------------------------------------------------------
// t2 = relu(t1@iw2^T+ib2); integ = tanh(t2@iw3^T+ib3); heads — R5-verified.
// ---------------------------------------------------------------------------
__global__ __launch_bounds__(64) void final_kernel(
    const float* __restrict__ t1, const float* __restrict__ iw2,
    const float* __restrict__ ib2, const float* __restrict__ iw3,
    const float* __restrict__ ib3,
    const float* __restrict__ hw_trend, const float* __restrict__ hb_trend,
    const float* __restrict__ hw_pat,   const float* __restrict__ hb_pat,
    const float* __restrict__ hw_key,   const float* __restrict__ hb_key,
    const float* __restrict__ hw_vol,   const float* __restrict__ hb_vol,
    const float* __restrict__ hw_conf,  const float* __restrict__ hb_conf,
    float* __restrict__ out)
{
    __shared__ float t1s[256], t2s[64], igs[32];
    int b = blockIdx.x, tid = threadIdx.x;
#pragma unroll
    for (int i = 0; i < 4; ++i) t1s[tid + i * 64] = t1[b * 256 + tid + i * 64];
    __syncthreads();
    float acc = ib2[tid];
#pragma unroll 4
    for (int k = 0; k < 256; ++k) acc = fmaf(t1s[k], iw2[tid * 256 + k], acc);
    t2s[tid] = fmaxf(acc, 0.f);
    __syncthreads();
    if (tid < 32) {
        float a2 = ib3[tid];
#pragma unroll 4
        for (int k = 0; k < 64; ++k) a2 = fmaf(t2s[k], iw3[tid * 64 + k], a2);
        igs[tid] = tanhft(a2);
    }
    __syncthreads();
    if (tid < 15) {
        const float* w; const float* bb; int j, off;
        if (tid < 3)        { w = hw_trend; bb = hb_trend; j = tid;     off = 0; }
        else if (tid < 9)   { w = hw_pat;   bb = hb_pat;   j = tid - 3; off = 3; }
        else if (tid < 13)  { w = hw_key;   bb = hb_key;   j = tid - 9; off = 9; }
        else if (tid == 13) { w = hw_vol;   bb = hb_vol;   j = 0;       off = 13; }
        else                { w = hw_conf;  bb = hb_conf;  j = 0;       off = 14; }
        float a3 = bb[j];
#pragma unroll
        for (int k = 0; k < 32; ++k) a3 = fmaf(igs[k], w[j * 32 + k], a3);
        out[b * 20 + off + j] = a3;
        if (tid == 14) out[b * 20 + 15] = sigf(a3);
    }
}

// ---------------------------------------------------------------------------
// group means of a (bf16, padded pitch 2528) -> out[:, 16:20]
// ---------------------------------------------------------------------------
__global__ __launch_bounds__(256) void means_kernel(
    const unsigned short* __restrict__ amat, float* __restrict__ out)
{
    __shared__ float red[256];
    int b = blockIdx.x, tid = threadIdx.x;
    float parts[4] = {0.f, 0.f, 0.f, 0.f};
    for (int n = tid; n < 2500; n += 256) {
        float v = bf2f(amat[b * 2528 + n]);
        if (n < 800)       parts[0] += v;
        else if (n < 1500) parts[1] += v;
        else if (n < 2100) parts[2] += v;
        else               parts[3] += v;
    }
    const float inv[4] = {1.f / 800.f, 1.f / 700.f, 1.f / 600.f, 1.f / 400.f};
#pragma unroll
    for (int g = 0; g < 4; ++g) {
        red[tid] = parts[g];
        __syncthreads();
        for (int s = 128; s > 0; s >>= 1) {
            if (tid < s) red[tid] += red[tid + s];
            __syncthreads();
        }
        if (tid == 0) out[b * 20 + 16 + g] = red[0] * inv[g];
        __syncthreads();
    }
}

// ---------------------------------------------------------------------------
extern "C" void kernel_launch(void* const* d_in, const int* in_sizes, int n_in,
                              void* d_out, int out_size, void* d_ws, size_t ws_size,
                              hipStream_t stream)
{
    const float* x        = (const float*)d_in[0];
    const int*   conn_idx = (const int*)  d_in[1];
    const float* w_ih0    = (const float*)d_in[2];
    const float* w_hh0    = (const float*)d_in[3];
    const float* b_ih0    = (const float*)d_in[4];
    const float* b_hh0    = (const float*)d_in[5];
    const float* w_ih1    = (const float*)d_in[6];
    const float* w_hh1    = (const float*)d_in[7];
    const float* b_ih1    = (const float*)d_in[8];
    const float* b_hh1    = (const float*)d_in[9];
    const float* pw1      = (const float*)d_in[10];
    const float* pb1      = (const float*)d_in[11];
    const float* pw2      = (const float*)d_in[12];
    const float* pb2      = (const float*)d_in[13];
    const float* conn_w   = (const float*)d_in[14];
    const float* sens     = (const float*)d_in[15];
    const float* thr      = (const float*)d_in[16];
    const float* iw1      = (const float*)d_in[17];
    const float* ib1      = (const float*)d_in[18];
    const float* iw2      = (const float*)d_in[19];
    const float* ib2      = (const float*)d_in[20];
    const float* iw3      = (const float*)d_in[21];
    const float* ib3      = (const float*)d_in[22];
    const float* hw_trend = (const float*)d_in[23];
    const float* hb_trend = (const float*)d_in[24];
    const float* hw_pat   = (const float*)d_in[25];
    const float* hb_pat   = (const float*)d_in[26];
    const float* hw_key   = (const float*)d_in[27];
    const float* hb_key   = (const float*)d_in[28];
    const float* hw_vol   = (const float*)d_in[29];
    const float* hb_vol   = (const float*)d_in[30];
    const float* hw_conf  = (const float*)d_in[31];
    const float* hb_conf  = (const float*)d_in[32];
    float* out = (float*)d_out;
    float* ws  = (float*)d_ws;

    // ws layout (float slots)
    unsigned short* whh0h = (unsigned short*)(ws);           // 32768 f
    unsigned short* wih1h = (unsigned short*)(ws + 32768);   // 32768 f
    unsigned short* whh1h = (unsigned short*)(ws + 65536);   // 32768 f
    float* bias0  = ws + 98304;   // 512
    float* bias1  = ws + 98816;   // 512
    float* h2     = ws + 99328;   // 131072
    float* base_  = ws + 230400;  // 32768
    float* weffT  = ws + 263168;  // 80000
    float* t1     = ws + 343168;  // 262144
    unsigned short* iw1b   = (unsigned short*)(ws + 605312); // 323584 f
    unsigned short* amatbf = (unsigned short*)(ws + 928896); // 1294336 f -> ends 2223232

    prep_kernel<<<258, 256, 0, stream>>>(w_hh0, w_ih1, w_hh1,
                                         b_ih0, b_hh0, b_ih1, b_hh1,
                                         whh0h, wih1h, whh1h, bias0, bias1);
    prep_iw1_kernel<<<2528, 256, 0, stream>>>(iw1, iw1b);
    lstm_kernel<<<256, 512, 0, stream>>>(x, whh0h, wih1h, whh1h, w_ih0,
                                         bias0, bias1, h2);
    phase2_kernel<<<1024, 64, 0, stream>>>(h2, pw1, pb1, pw2, pb2, base_);
    weff_kernel<<<20, 128, 0, stream>>>(conn_idx, conn_w, weffT);
    za_kernel<<<640, 256, 0, stream>>>(base_, weffT, sens, thr, amatbf);
    gemm_iw1_kernel<<<dim3(4, 32), 128, 0, stream>>>(amatbf, iw1b, ib1, t1);
    final_kernel<<<1024, 64, 0, stream>>>(t1, iw2, ib2, iw3, ib3,
                                          hw_trend, hb_trend, hw_pat, hb_pat,
                                          hw_key, hb_key, hw_vol, hb_vol,
                                          hw_conf, hb_conf, out);
    means_kernel<<<1024, 256, 0, stream>>>(amatbf, out);
}